// Round 4
// baseline (286300.586 us; speedup 1.0000x reference)
//
#include <hip/hip_runtime.h>
#include <hip/hip_bf16.h>

// StrokeRecoveryModel: S=256 seq steps, B=64, E=1024, H=4, D=256, V=5.
// Round 4: FULL-fp32 pipeline. Rounds 1/3 showed bf16 K/V quantization gets
// chaos-amplified (~3e-3/step -> ~0.4 by step 256; loop gain ~1.03-1.1).
// So: fp32 K/V in ws, fp32 internal math, NO intermediate quantization.
// Inputs read via per-input dtype flags (detector kept as a zero-cost hedge;
// all-fp32 expected -> flags 0 -> plain float4 loads).
// Per step: p1 (gate partials + q + prev out head) -> attn -> oproj -> lstm1 -> lstm2

#define S_LEN 256

// float-element offsets in ws
#define OFF_H1    0
#define OFF_C1    65536
#define OFF_H2    131072
#define OFF_C2    196608
#define OFF_Q     262144
#define OFF_CR    327680            // ctx raw (pre o-proj)
#define OFF_CX    393216            // ctx projected
#define OFF_G1    458752            // 262144
#define OFF_G2    720896            // 262144
#define OFF_B1C   983040            // 4096
#define OFF_B2C   987136            // 4096
#define OFF_BQ    991232            // 3072
#define OFF_BO    994304            // 1024
#define OFF_BOUT  995328            // 8
#define OFF_FLAGS 995336            // 16 ints
#define OFF_KT    995360            // 16,777,216 floats (16B aligned)
#define OFF_VB    (995360 + 16777216)
#define WS_FLOATS (995360ull + 2ull * 16777216ull)
#define WS_NEED   (WS_FLOATS * 4ull)   // ~131.8 MiB (round-3's 123.6 MiB check passed)

typedef unsigned int uint;
typedef unsigned short ushort;

__device__ __forceinline__ float sigm(float x) { return 1.f / (1.f + __expf(-x)); }
__device__ __forceinline__ float bfl(uint u) { return __uint_as_float(u << 16); }
__device__ __forceinline__ float bfh(uint u) { return __uint_as_float(u & 0xffff0000u); }

// flag-branched loads: bf=1 -> buffer is bf16, upconvert; bf=0 -> plain fp32.
// branch is wave-uniform (flag from SGPR) => ~free.
__device__ __forceinline__ float4 ld4f(const void* p, size_t i, int bf) {
  if (bf) {
    uint2 u = *(const uint2*)((const ushort*)p + i);
    return make_float4(bfl(u.x), bfh(u.x), bfl(u.y), bfh(u.y));
  }
  return *(const float4*)((const float*)p + i);
}
__device__ __forceinline__ float ld1f(const void* p, size_t i, int bf) {
  if (bf) return __uint_as_float(((uint)((const ushort*)p)[i]) << 16);
  return ((const float*)p)[i];
}

// ---------------------------------------------------------------------------
// dtype detector (1 wave): bf16 buffer -> low-16 pseudo-exponent in [96,134]
// ~100% of the time for normal data; fp32 buffer -> ~15% (uniform mantissa).
// ---------------------------------------------------------------------------
struct Ptrs { const void* p[15]; int n[15]; };

__global__ __launch_bounds__(64) void detect_kernel(Ptrs pp, int* flags) {
  int lane = threadIdx.x;
  for (int i = 0; i < 15; i++) {
    int nw = pp.n[i] / 2;
    if (nw > 64) nw = 64;
    int pass = 0;
    if (lane < nw) {
      uint w = ((const uint*)pp.p[i])[lane];
      uint ex = (w >> 7) & 0xFFu;
      pass = (ex >= 96u && ex <= 134u) ? 1 : 0;
    }
    unsigned long long bal = __ballot(pass);
    int cnt = __popcll(bal);
    if (lane == 0) flags[i] = (cnt * 4 >= nw * 3) ? 1 : 0;
  }
}

// bias canonicalization to fp32 scratch
__global__ __launch_bounds__(256) void bias_cvt(
    const void* bqkv, const void* bo, const void* bih1, const void* bhh1,
    const void* bih2, const void* bhh2, const void* bout, const int* __restrict__ flags,
    float* bqF, float* boF, float* b1c, float* b2c, float* boutF) {
  int j = blockIdx.x * 256 + threadIdx.x;
  if (j < 3072) bqF[j] = ld1f(bqkv, j, flags[2]);
  if (j < 1024) boF[j] = ld1f(bo, j, flags[4]);
  if (j < 4096) {
    b1c[j] = ld1f(bih1, j, flags[7]) + ld1f(bhh1, j, flags[8]);
    b2c[j] = ld1f(bih2, j, flags[11]) + ld1f(bhh2, j, flags[12]);
  }
  if (j < 5) boutF[j] = ld1f(bout, j, flags[14]);
}

// ---------------------------------------------------------------------------
// KV GEMM: C[16384,2048] = cnn[16384,1024] @ w_qkv[1024:3072,:]^T (+bias),
// scatter-stored fp32: n<1024 -> Kt[pair][d][s], n>=1024 -> Vb[pair][s][d]
// ---------------------------------------------------------------------------
__global__ __launch_bounds__(256) void kv_gemm(
    const void* __restrict__ A, const void* __restrict__ Wq,
    const int* __restrict__ flags, const float* __restrict__ bqF,
    float* __restrict__ Kt, float* __restrict__ Vb) {
  __shared__ float sA[16][65];
  __shared__ float sB[16][65];
  int f0 = flags[0], f1 = flags[1];
  int m0 = blockIdx.y << 6;
  int n0 = blockIdx.x << 6;
  int t = threadIdx.x;
  int lm = t >> 2, lk = (t & 3) << 2;
  int tx = t & 15, ty = t >> 4;
  float acc[4][4] = {};
  for (int k0 = 0; k0 < 1024; k0 += 16) {
    float4 a4 = ld4f(A, (size_t)(m0 + lm) * 1024 + k0 + lk, f0);
    float4 b4 = ld4f(Wq, (size_t)(1024 + n0 + lm) * 1024 + k0 + lk, f1);
    __syncthreads();
    sA[lk + 0][lm] = a4.x; sA[lk + 1][lm] = a4.y; sA[lk + 2][lm] = a4.z; sA[lk + 3][lm] = a4.w;
    sB[lk + 0][lm] = b4.x; sB[lk + 1][lm] = b4.y; sB[lk + 2][lm] = b4.z; sB[lk + 3][lm] = b4.w;
    __syncthreads();
#pragma unroll
    for (int k = 0; k < 16; k++) {
      float av[4], bv[4];
#pragma unroll
      for (int i = 0; i < 4; i++) av[i] = sA[k][ty * 4 + i];
#pragma unroll
      for (int j = 0; j < 4; j++) bv[j] = sB[k][tx * 4 + j];
#pragma unroll
      for (int i = 0; i < 4; i++)
#pragma unroll
        for (int j = 0; j < 4; j++) acc[i][j] += av[i] * bv[j];
    }
  }
#pragma unroll
  for (int i = 0; i < 4; i++) {
    int m = m0 + ty * 4 + i;
    int s = m >> 6, b = m & 63;
#pragma unroll
    for (int j = 0; j < 4; j++) {
      int n = n0 + tx * 4 + j;
      float v = acc[i][j];
      if (n < 1024) {
        int h = n >> 8, d = n & 255;
        v += bqF[1024 + n];
        Kt[((size_t)(((b << 2) | h) << 8 | d) << 8) | s] = v;
      } else {
        int nn = n - 1024;
        int h = nn >> 8, d = nn & 255;
        v += bqF[2048 + nn];
        Vb[((size_t)(((b << 2) | h) << 8 | s) << 8) | d] = v;
      }
    }
  }
}

// ---------------------------------------------------------------------------
// P1: blocks 0..1023:  g1p = h2@w_ih1[:, :1024].T + h1@w_hh1.T + b1c
//                      g2p = h2@w_hh2.T + b2c
//     blocks 1024..1279: q = h2@w_q.T + b_q
//     blocks 1280..1343: out head for step s-1 (skipped at s==0)
// ---------------------------------------------------------------------------
__global__ __launch_bounds__(256) void p1_kernel(
    const float* __restrict__ h1, const float* __restrict__ h2,
    const void* __restrict__ wih1, const void* __restrict__ whh1,
    const void* __restrict__ whh2, const void* __restrict__ wqkv,
    const void* __restrict__ wout, const int* __restrict__ flags,
    const float* __restrict__ b1c, const float* __restrict__ b2c,
    const float* __restrict__ bqF, const float* __restrict__ boutF,
    float* __restrict__ g1p, float* __restrict__ g2p,
    float* __restrict__ qbuf, float* __restrict__ out, int s) {
  __shared__ float smem[2048];
  int bi = blockIdx.x, t = threadIdx.x;
  if (bi < 1024) {
    int f5 = flags[5], f6 = flags[6], f10 = flags[10];
    int b = bi & 63, jt = bi >> 6;
    float4* s2 = (float4*)smem;
    float4* s1 = (float4*)(smem + 1024);
    s2[t] = ((const float4*)(h2 + (b << 10)))[t];
    s1[t] = ((const float4*)(h1 + (b << 10)))[t];
    __syncthreads();
    int j = (jt << 8) + t;
    size_t ra = (size_t)j * 2048, rb = (size_t)j * 1024;
    float a1 = 0.f, a3 = 0.f;
#pragma unroll 2
    for (int i = 0; i < 256; i++) {
      float4 A4 = ld4f(wih1, ra + 4 * i, f5);
      float4 B4 = ld4f(whh1, rb + 4 * i, f6);
      float4 C4 = ld4f(whh2, rb + 4 * i, f10);
      float4 x2 = s2[i], x1 = s1[i];
      a1 += x2.x * A4.x + x2.y * A4.y + x2.z * A4.z + x2.w * A4.w;
      a1 += x1.x * B4.x + x1.y * B4.y + x1.z * B4.z + x1.w * B4.w;
      a3 += x2.x * C4.x + x2.y * C4.y + x2.z * C4.z + x2.w * C4.w;
    }
    g1p[(b << 12) + j] = a1 + b1c[j];
    g2p[(b << 12) + j] = a3 + b2c[j];
  } else if (bi < 1280) {
    int f1 = flags[1];
    int idx = bi - 1024;
    int b = idx & 63, dt = idx >> 6;
    float4* s2 = (float4*)smem;
    s2[t] = ((const float4*)(h2 + (b << 10)))[t];
    __syncthreads();
    int col = (dt << 8) + t;
    size_t r = (size_t)col * 1024;
    float acc = 0.f;
#pragma unroll 4
    for (int i = 0; i < 256; i++) {
      float4 w4 = ld4f(wqkv, r + 4 * i, f1);
      float4 x = s2[i];
      acc += x.x * w4.x + x.y * w4.y + x.z * w4.z + x.w * w4.w;
    }
    qbuf[(b << 10) + col] = acc + bqF[col];
  } else {
    if (s == 0) return;
    int f13 = flags[13];
    int b = bi - 1280;
    float p[5] = {0.f, 0.f, 0.f, 0.f, 0.f};
#pragma unroll
    for (int k2 = 0; k2 < 4; k2++) {
      float hv = h2[(b << 10) + t + (k2 << 8)];
#pragma unroll
      for (int v = 0; v < 5; v++)
        p[v] += hv * ld1f(wout, (size_t)(v << 10) + t + (k2 << 8), f13);
    }
#pragma unroll
    for (int v = 0; v < 5; v++) smem[v * 256 + t] = p[v];
    __syncthreads();
    if (t < 5) {
      float acc = boutF[t];
      for (int i = 0; i < 256; i++) acc += smem[t * 256 + i];
      if (t >= 2) acc = sigm(acc);
      out[((s - 1) * 64 + b) * 5 + t] = acc;
    }
  }
}

// ---------------------------------------------------------------------------
// Attention (fp32 K/V): one block per (b,h); t = score index s, then ctx d.
// ---------------------------------------------------------------------------
__global__ __launch_bounds__(256) void attn_kernel(
    const float* __restrict__ qbuf, const float* __restrict__ Kt,
    const float* __restrict__ Vb, float* __restrict__ cr) {
  __shared__ float lq[256];
  __shared__ float latt[256];
  __shared__ float red[8];
  int p = blockIdx.x, t = threadIdx.x;
  int b = p >> 2, h = p & 3;
  lq[t] = qbuf[(b << 10) + (h << 8) + t];
  __syncthreads();
  const float* Kp = Kt + ((size_t)p << 16);
  float sc = 0.f;
#pragma unroll 4
  for (int d = 0; d < 256; d++) sc += lq[d] * Kp[(d << 8) + t];
  sc *= 0.0625f;  // 1/sqrt(256)
  float m = sc;
#pragma unroll
  for (int o = 32; o >= 1; o >>= 1) m = fmaxf(m, __shfl_xor(m, o, 64));
  if ((t & 63) == 0) red[t >> 6] = m;
  __syncthreads();
  m = fmaxf(fmaxf(red[0], red[1]), fmaxf(red[2], red[3]));
  float e = __expf(sc - m);
  float ss = e;
#pragma unroll
  for (int o = 32; o >= 1; o >>= 1) ss += __shfl_xor(ss, o, 64);
  if ((t & 63) == 0) red[4 + (t >> 6)] = ss;
  __syncthreads();
  ss = red[4] + red[5] + red[6] + red[7];
  latt[t] = e / ss;
  __syncthreads();
  const float* Vp = Vb + ((size_t)p << 16);
  float cv = 0.f;
#pragma unroll 4
  for (int s2 = 0; s2 < 256; s2++) cv += latt[s2] * Vp[(s2 << 8) + t];
  cr[(b << 10) + (h << 8) + t] = cv;
}

// ---------------------------------------------------------------------------
// o-proj: cx[b,col] = ctxraw[b,:] . w_o[col,:] + b_o[col]
// ---------------------------------------------------------------------------
__global__ __launch_bounds__(256) void oproj_kernel(
    const float* __restrict__ cr, const void* __restrict__ wo,
    const int* __restrict__ flags, const float* __restrict__ boF,
    float* __restrict__ cx) {
  __shared__ float lx[1024];
  int idx = blockIdx.x, b = idx & 63, dt = idx >> 6, t = threadIdx.x;
  ((float4*)lx)[t] = ((const float4*)(cr + (b << 10)))[t];
  __syncthreads();
  int f3 = flags[3];
  int col = (dt << 8) + t;
  size_t r = (size_t)col * 1024;
  float acc = 0.f;
#pragma unroll 4
  for (int i = 0; i < 256; i++) {
    float4 w4 = ld4f(wo, r + 4 * i, f3);
    float4 x = ((float4*)lx)[i];
    acc += x.x * w4.x + x.y * w4.y + x.z * w4.z + x.w * w4.w;
  }
  cx[(b << 10) + col] = acc + boF[col];
}

// ---------------------------------------------------------------------------
// LSTM cell: g = gpart + xin @ W.T (gate rows i|f|g|o of 1024; row stride /
// column offset parameterized so w_ih1's [:,1024:2048] slice works directly)
// ---------------------------------------------------------------------------
__global__ __launch_bounds__(256) void lstm_kernel(
    const float* __restrict__ xin, const void* __restrict__ Wg,
    const int* __restrict__ flags, int fidx, int rowStride, int colOff,
    const float* __restrict__ gpart, float* __restrict__ cbuf,
    float* __restrict__ hbuf) {
  __shared__ float lx[1024];
  int b = blockIdx.x >> 2, j0 = (blockIdx.x & 3) << 8;
  int t = threadIdx.x;
  ((float4*)lx)[t] = ((const float4*)(xin + (b << 10)))[t];
  __syncthreads();
  int bf = flags[fidx];
  int j = j0 + t;
  float g[4];
#pragma unroll
  for (int gi = 0; gi < 4; gi++) {
    size_t r = (size_t)((gi << 10) + j) * rowStride + colOff;
    float acc = 0.f;
#pragma unroll 4
    for (int i = 0; i < 256; i++) {
      float4 w4 = ld4f(Wg, r + 4 * i, bf);
      float4 x = ((float4*)lx)[i];
      acc += x.x * w4.x + x.y * w4.y + x.z * w4.z + x.w * w4.w;
    }
    g[gi] = gpart[(b << 12) + (gi << 10) + j] + acc;
  }
  float gi_ = sigm(g[0]);
  float gf_ = sigm(g[1]);
  float gg_ = tanhf(g[2]);
  float go_ = sigm(g[3]);
  float c = gf_ * cbuf[(b << 10) + j] + gi_ * gg_;
  cbuf[(b << 10) + j] = c;
  hbuf[(b << 10) + j] = go_ * tanhf(c);
}

// final output head (step 255)
__global__ __launch_bounds__(256) void outhead_kernel(
    const float* __restrict__ h2, const void* __restrict__ wout,
    const int* __restrict__ flags, const float* __restrict__ boutF,
    float* __restrict__ out, int row) {
  __shared__ float smem[1280];
  int b = blockIdx.x, t = threadIdx.x;
  int f13 = flags[13];
  float p[5] = {0.f, 0.f, 0.f, 0.f, 0.f};
#pragma unroll
  for (int k2 = 0; k2 < 4; k2++) {
    float hv = h2[(b << 10) + t + (k2 << 8)];
#pragma unroll
    for (int v = 0; v < 5; v++)
      p[v] += hv * ld1f(wout, (size_t)(v << 10) + t + (k2 << 8), f13);
  }
#pragma unroll
  for (int v = 0; v < 5; v++) smem[v * 256 + t] = p[v];
  __syncthreads();
  if (t < 5) {
    float acc = boutF[t];
    for (int i = 0; i < 256; i++) acc += smem[t * 256 + i];
    if (t >= 2) acc = sigm(acc);
    out[(row * 64 + b) * 5 + t] = acc;
  }
}

extern "C" void kernel_launch(void* const* d_in, const int* in_sizes, int n_in,
                              void* d_out, int out_size, void* d_ws, size_t ws_size,
                              hipStream_t stream) {
  float* out = (float*)d_out;
  if (ws_size < WS_NEED) return;  // loud failure: output stays zero -> absmax 1.195

  float* W = (float*)d_ws;
  float* h1    = W + OFF_H1;
  float* c1    = W + OFF_C1;
  float* h2    = W + OFF_H2;
  float* c2    = W + OFF_C2;
  float* qv    = W + OFF_Q;
  float* cr    = W + OFF_CR;
  float* cx    = W + OFF_CX;
  float* g1p   = W + OFF_G1;
  float* g2p   = W + OFF_G2;
  float* b1c   = W + OFF_B1C;
  float* b2c   = W + OFF_B2C;
  float* bqF   = W + OFF_BQ;
  float* boF   = W + OFF_BO;
  float* boutF = W + OFF_BOUT;
  int*   flags = (int*)(W + OFF_FLAGS);
  float* Kt    = W + OFF_KT;
  float* Vb    = W + OFF_VB;

  // zero initial state h1,c1,h2,c2 (contiguous 1 MB)
  hipMemsetAsync(d_ws, 0, 4 * 65536 * sizeof(float), stream);

  // dtype detection + bias canonicalization
  Ptrs pp;
  for (int i = 0; i < 15; i++) { pp.p[i] = d_in[i]; pp.n[i] = in_sizes[i]; }
  detect_kernel<<<1, 64, 0, stream>>>(pp, flags);
  bias_cvt<<<16, 256, 0, stream>>>(d_in[2], d_in[4], d_in[7], d_in[8],
                                   d_in[11], d_in[12], d_in[14], flags,
                                   bqF, boF, b1c, b2c, boutF);

  // one-time K/V precompute (fp32)
  kv_gemm<<<dim3(32, 256), 256, 0, stream>>>(d_in[0], d_in[1], flags, bqF, Kt, Vb);

  for (int s = 0; s < S_LEN; s++) {
    p1_kernel<<<1344, 256, 0, stream>>>(h1, h2, d_in[5], d_in[6], d_in[10],
                                        d_in[1], d_in[13], flags, b1c, b2c,
                                        bqF, boutF, g1p, g2p, qv, out, s);
    attn_kernel<<<256, 256, 0, stream>>>(qv, Kt, Vb, cr);
    oproj_kernel<<<256, 256, 0, stream>>>(cr, d_in[3], flags, boF, cx);
    lstm_kernel<<<256, 256, 0, stream>>>(cx, d_in[5], flags, 5, 2048, 1024, g1p, c1, h1);
    lstm_kernel<<<256, 256, 0, stream>>>(h1, d_in[9], flags, 9, 1024, 0, g2p, c2, h2);
  }
  outhead_kernel<<<64, 256, 0, stream>>>(h2, d_in[13], flags, boutF, out, 255);
}

// Round 5
// 50078.961 us; speedup vs baseline: 5.7170x; 5.7170x over previous
//
#include <hip/hip_runtime.h>
#include <hip/hip_bf16.h>

// StrokeRecoveryModel: S=256 seq steps, B=64, E=1024, H=4, D=256, V=5.
// Round 5: keep round-4 numerics (fp32 everywhere — proven absmax 0.0039),
// fix the memory structure: per-step matmuls are now tiled GEMMs where each
// block covers ALL 64 batch rows x a 64-col tile, so weights stream once per
// step (~96 MB) instead of once per batch element (~5.7 GB). K-split-4 on the
// serial-chain GEMMs for full-chip grids. o-proj folded into LSTM1 via fp32
// Weff = w_ih1[:,1024:] @ w_o (+ b1c fold). Dual path: if ws_size < fast-path
// need (158.9 MB), fall back to the proven round-4 path.

#define S_LEN 256

// ---------------- slow-path (round-4) layout: proven to fit ----------------
#define OFF_H1    0
#define OFF_C1    65536
#define OFF_H2    131072
#define OFF_C2    196608
#define OFF_Q     262144
#define OFF_CR    327680
#define OFF_CX    393216
#define OFF_G1    458752
#define OFF_G2    720896
#define OFF_B1C   983040
#define OFF_B2C   987136
#define OFF_BQ    991232
#define OFF_BO    994304
#define OFF_BOUT  995328
#define OFF_FLAGS 995336
#define OFF_KT    995360
#define OFF_VB    (995360 + 16777216)
#define WS_FLOATS (995360ull + 2ull * 16777216ull)
#define WS_NEED   (WS_FLOATS * 4ull)          // 138,199,168 B (proven OK in r4)

// ---------------- fast-path layout ----------------
#define FOFF_QV    262144
#define FOFF_CR    327680
#define FOFF_G1P   393216
#define FOFF_G2P   655360
#define FOFF_P     917504          // 4 x 262144 lstm K-split partials (shared)
#define FOFF_B1C   1966080
#define FOFF_B2C   1970176
#define FOFF_BQ    1974272
#define FOFF_BO    1977344
#define FOFF_BOUT  1978368
#define FOFF_FLAGS 1978376
#define FOFF_WEFF  1978400         // 4096x1024 fp32
#define FOFF_KT    6172704
#define FOFF_VB    22949920
#define FWS_FLOATS 39727136ull
#define FWS_NEED   (FWS_FLOATS * 4ull)        // 158,908,544 B

typedef unsigned int uint;
typedef unsigned short ushort;

__device__ __forceinline__ float sigm(float x) { return 1.f / (1.f + __expf(-x)); }
__device__ __forceinline__ float bfl(uint u) { return __uint_as_float(u << 16); }
__device__ __forceinline__ float bfh(uint u) { return __uint_as_float(u & 0xffff0000u); }

// flag-branched loads (wave-uniform flag => ~free)
__device__ __forceinline__ float4 ld4f(const void* p, size_t i, int bf) {
  if (bf) {
    uint2 u = *(const uint2*)((const ushort*)p + i);
    return make_float4(bfl(u.x), bfh(u.x), bfl(u.y), bfh(u.y));
  }
  return *(const float4*)((const float*)p + i);
}
__device__ __forceinline__ float ld1f(const void* p, size_t i, int bf) {
  if (bf) return __uint_as_float(((uint)((const ushort*)p)[i]) << 16);
  return ((const float*)p)[i];
}

// ---------------------------------------------------------------------------
// dtype detector + bias canonicalization (shared by both paths)
// ---------------------------------------------------------------------------
struct Ptrs { const void* p[15]; int n[15]; };

__global__ __launch_bounds__(64) void detect_kernel(Ptrs pp, int* flags) {
  int lane = threadIdx.x;
  for (int i = 0; i < 15; i++) {
    int nw = pp.n[i] / 2;
    if (nw > 64) nw = 64;
    int pass = 0;
    if (lane < nw) {
      uint w = ((const uint*)pp.p[i])[lane];
      uint ex = (w >> 7) & 0xFFu;
      pass = (ex >= 96u && ex <= 134u) ? 1 : 0;
    }
    unsigned long long bal = __ballot(pass);
    int cnt = __popcll(bal);
    if (lane == 0) flags[i] = (cnt * 4 >= nw * 3) ? 1 : 0;
  }
}

__global__ __launch_bounds__(256) void bias_cvt(
    const void* bqkv, const void* bo, const void* bih1, const void* bhh1,
    const void* bih2, const void* bhh2, const void* bout, const int* __restrict__ flags,
    float* bqF, float* boF, float* b1c, float* b2c, float* boutF) {
  int j = blockIdx.x * 256 + threadIdx.x;
  if (j < 3072) bqF[j] = ld1f(bqkv, j, flags[2]);
  if (j < 1024) boF[j] = ld1f(bo, j, flags[4]);
  if (j < 4096) {
    b1c[j] = ld1f(bih1, j, flags[7]) + ld1f(bhh1, j, flags[8]);
    b2c[j] = ld1f(bih2, j, flags[11]) + ld1f(bhh2, j, flags[12]);
  }
  if (j < 5) boutF[j] = ld1f(bout, j, flags[14]);
}

// b1c[j] += sum_m wih1[j,1024+m] * b_o[m]   (o-proj bias fold, fast path)
__global__ __launch_bounds__(256) void bias_fold(
    const void* __restrict__ wih1, const int* __restrict__ flags,
    const float* __restrict__ boF, float* __restrict__ b1c) {
  __shared__ float lbo[1024];
  int t = threadIdx.x;
  ((float4*)lbo)[t] = ((const float4*)boF)[t];
  __syncthreads();
  int f5 = flags[5];
  int j = blockIdx.x * 256 + t;
  size_t r = (size_t)j * 2048 + 1024;
  float acc = 0.f;
#pragma unroll 4
  for (int i = 0; i < 256; i++) {
    float4 w4 = ld4f(wih1, r + 4 * i, f5);
    float4 x4 = ((float4*)lbo)[i];
    acc += w4.x * x4.x + w4.y * x4.y + w4.z * x4.z + w4.w * x4.w;
  }
  b1c[j] += acc;
}

// ---------------------------------------------------------------------------
// KV GEMM (shared): C[16384,2048] = cnn @ w_qkv[1024:3072]^T (+bias),
// scatter fp32: n<1024 -> Kt[pair][d][s], else Vb[pair][s][d]
// ---------------------------------------------------------------------------
__global__ __launch_bounds__(256) void kv_gemm(
    const void* __restrict__ A, const void* __restrict__ Wq,
    const int* __restrict__ flags, const float* __restrict__ bqF,
    float* __restrict__ Kt, float* __restrict__ Vb) {
  __shared__ float sA[16][65];
  __shared__ float sB[16][65];
  int f0 = flags[0], f1 = flags[1];
  int m0 = blockIdx.y << 6;
  int n0 = blockIdx.x << 6;
  int t = threadIdx.x;
  int lm = t >> 2, lk = (t & 3) << 2;
  int tx = t & 15, ty = t >> 4;
  float acc[4][4] = {};
  for (int k0 = 0; k0 < 1024; k0 += 16) {
    float4 a4 = ld4f(A, (size_t)(m0 + lm) * 1024 + k0 + lk, f0);
    float4 b4 = ld4f(Wq, (size_t)(1024 + n0 + lm) * 1024 + k0 + lk, f1);
    __syncthreads();
    sA[lk + 0][lm] = a4.x; sA[lk + 1][lm] = a4.y; sA[lk + 2][lm] = a4.z; sA[lk + 3][lm] = a4.w;
    sB[lk + 0][lm] = b4.x; sB[lk + 1][lm] = b4.y; sB[lk + 2][lm] = b4.z; sB[lk + 3][lm] = b4.w;
    __syncthreads();
#pragma unroll
    for (int k = 0; k < 16; k++) {
      float av[4], bv[4];
#pragma unroll
      for (int i = 0; i < 4; i++) av[i] = sA[k][ty * 4 + i];
#pragma unroll
      for (int j = 0; j < 4; j++) bv[j] = sB[k][tx * 4 + j];
#pragma unroll
      for (int i = 0; i < 4; i++)
#pragma unroll
        for (int j = 0; j < 4; j++) acc[i][j] += av[i] * bv[j];
    }
  }
#pragma unroll
  for (int i = 0; i < 4; i++) {
    int m = m0 + ty * 4 + i;
    int s = m >> 6, b = m & 63;
#pragma unroll
    for (int j = 0; j < 4; j++) {
      int n = n0 + tx * 4 + j;
      float v = acc[i][j];
      if (n < 1024) {
        int h = n >> 8, d = n & 255;
        v += bqF[1024 + n];
        Kt[((size_t)(((b << 2) | h) << 8 | d) << 8) | s] = v;
      } else {
        int nn = n - 1024;
        int h = nn >> 8, d = nn & 255;
        v += bqF[2048 + nn];
        Vb[((size_t)(((b << 2) | h) << 8 | s) << 8) | d] = v;
      }
    }
  }
}

// ---------------------------------------------------------------------------
// Weff[4096,1024] = wih1[:,1024:2048] @ w_o   (fp32 out, fast path, one-time)
// ---------------------------------------------------------------------------
__global__ __launch_bounds__(256) void weff_gemm(
    const void* __restrict__ wih1, const void* __restrict__ wo,
    const int* __restrict__ flags, float* __restrict__ Weff) {
  __shared__ float sA[16][65];
  __shared__ float sB[16][65];
  int f5 = flags[5], f3 = flags[3];
  int m0 = blockIdx.y << 6;
  int n0 = blockIdx.x << 6;
  int t = threadIdx.x;
  int lm = t >> 2, lk = (t & 3) << 2;
  int kk = t >> 4, nn2 = (t & 15) << 2;
  int tx = t & 15, ty = t >> 4;
  float acc[4][4] = {};
  for (int k0 = 0; k0 < 1024; k0 += 16) {
    float4 a4 = ld4f(wih1, (size_t)(m0 + lm) * 2048 + 1024 + k0 + lk, f5);
    float4 b4 = ld4f(wo, (size_t)(k0 + kk) * 1024 + n0 + nn2, f3);
    __syncthreads();
    sA[lk + 0][lm] = a4.x; sA[lk + 1][lm] = a4.y; sA[lk + 2][lm] = a4.z; sA[lk + 3][lm] = a4.w;
    sB[kk][nn2 + 0] = b4.x; sB[kk][nn2 + 1] = b4.y; sB[kk][nn2 + 2] = b4.z; sB[kk][nn2 + 3] = b4.w;
    __syncthreads();
#pragma unroll
    for (int k = 0; k < 16; k++) {
      float av[4], bv[4];
#pragma unroll
      for (int i = 0; i < 4; i++) av[i] = sA[k][ty * 4 + i];
#pragma unroll
      for (int j = 0; j < 4; j++) bv[j] = sB[k][tx * 4 + j];
#pragma unroll
      for (int i = 0; i < 4; i++)
#pragma unroll
        for (int j = 0; j < 4; j++) acc[i][j] += av[i] * bv[j];
    }
  }
#pragma unroll
  for (int i = 0; i < 4; i++)
#pragma unroll
    for (int j = 0; j < 4; j++)
      Weff[(size_t)(m0 + ty * 4 + i) * 1024 + n0 + tx * 4 + j] = acc[i][j];
}

// ---------------------------------------------------------------------------
// FAST p1: grid 208. blocks 0..63: g1p tile (K=2048: h2|wih1_left then
// h1|whh1), +b1c. 64..127: g2p (h2@whh2^T)+b2c. 128..143: q (h2@wq^T)+bq.
// 144..207: out head for step s-1.
// All GEMM tiles: 64 batch rows x 64 cols, 256 thr, 4x4 acc, k-chunks of 32.
// ---------------------------------------------------------------------------
__global__ __launch_bounds__(256) void p1_fast(
    const float* __restrict__ h1, const float* __restrict__ h2,
    const void* __restrict__ wih1, const void* __restrict__ whh1,
    const void* __restrict__ whh2, const void* __restrict__ wqkv,
    const void* __restrict__ wout, const int* __restrict__ flags,
    const float* __restrict__ b1c, const float* __restrict__ b2c,
    const float* __restrict__ bqF, const float* __restrict__ boutF,
    float* __restrict__ g1p, float* __restrict__ g2p,
    float* __restrict__ qv, float* __restrict__ out, int s) {
  __shared__ __align__(16) float sX[32][68];
  __shared__ __align__(16) float sW[32][68];
  int bi = blockIdx.x, t = threadIdx.x;

  if (bi >= 144) {  // ---- out head for step s-1 ----
    if (s == 0) return;
    float* smem = &sX[0][0];  // reuse LDS (needs 1280 floats)
    int f13 = flags[13];
    int b = bi - 144;
    float p[5] = {0.f, 0.f, 0.f, 0.f, 0.f};
#pragma unroll
    for (int k2 = 0; k2 < 4; k2++) {
      float hv = h2[(b << 10) + t + (k2 << 8)];
#pragma unroll
      for (int v = 0; v < 5; v++)
        p[v] += hv * ld1f(wout, (size_t)(v << 10) + t + (k2 << 8), f13);
    }
#pragma unroll
    for (int v = 0; v < 5; v++) smem[v * 256 + t] = p[v];
    __syncthreads();
    if (t < 5) {
      float acc = boutF[t];
      for (int i = 0; i < 256; i++) acc += smem[t * 256 + i];
      if (t >= 2) acc = sigm(acc);
      out[((s - 1) * 64 + b) * 5 + t] = acc;
    }
    return;
  }

  int lm = t >> 2, lk8 = (t & 3) << 3;
  int tx = t & 15, ty = t >> 4;
  float acc[4][4] = {};

  int kind = (bi < 64) ? 0 : (bi < 128) ? 1 : 2;
  int n0 = (kind == 0) ? (bi << 6) : (kind == 1) ? ((bi - 64) << 6) : ((bi - 128) << 6);
  int Ktot = (kind == 0) ? 2048 : 1024;

  for (int k0 = 0; k0 < Ktot; k0 += 32) {
    const float* xs;
    const void* Wm;
    size_t wstride;
    int koff, bf;
    if (kind == 0) {
      if (k0 < 1024) { xs = h2; Wm = wih1; wstride = 2048; koff = k0; bf = flags[5]; }
      else           { xs = h1; Wm = whh1; wstride = 1024; koff = k0 - 1024; bf = flags[6]; }
    } else if (kind == 1) { xs = h2; Wm = whh2; wstride = 1024; koff = k0; bf = flags[10]; }
    else                  { xs = h2; Wm = wqkv; wstride = 1024; koff = k0; bf = flags[1]; }

    float4 xa = *(const float4*)(xs + (lm << 10) + koff + lk8);
    float4 xb = *(const float4*)(xs + (lm << 10) + koff + lk8 + 4);
    float4 wa = ld4f(Wm, (size_t)(n0 + lm) * wstride + koff + lk8, bf);
    float4 wb = ld4f(Wm, (size_t)(n0 + lm) * wstride + koff + lk8 + 4, bf);
    __syncthreads();
    sX[lk8 + 0][lm] = xa.x; sX[lk8 + 1][lm] = xa.y; sX[lk8 + 2][lm] = xa.z; sX[lk8 + 3][lm] = xa.w;
    sX[lk8 + 4][lm] = xb.x; sX[lk8 + 5][lm] = xb.y; sX[lk8 + 6][lm] = xb.z; sX[lk8 + 7][lm] = xb.w;
    sW[lk8 + 0][lm] = wa.x; sW[lk8 + 1][lm] = wa.y; sW[lk8 + 2][lm] = wa.z; sW[lk8 + 3][lm] = wa.w;
    sW[lk8 + 4][lm] = wb.x; sW[lk8 + 5][lm] = wb.y; sW[lk8 + 6][lm] = wb.z; sW[lk8 + 7][lm] = wb.w;
    __syncthreads();
#pragma unroll
    for (int k = 0; k < 32; k++) {
      float4 av = *(const float4*)&sX[k][ty << 2];
      float4 bv = *(const float4*)&sW[k][tx << 2];
      acc[0][0] += av.x * bv.x; acc[0][1] += av.x * bv.y; acc[0][2] += av.x * bv.z; acc[0][3] += av.x * bv.w;
      acc[1][0] += av.y * bv.x; acc[1][1] += av.y * bv.y; acc[1][2] += av.y * bv.z; acc[1][3] += av.y * bv.w;
      acc[2][0] += av.z * bv.x; acc[2][1] += av.z * bv.y; acc[2][2] += av.z * bv.z; acc[2][3] += av.z * bv.w;
      acc[3][0] += av.w * bv.x; acc[3][1] += av.w * bv.y; acc[3][2] += av.w * bv.z; acc[3][3] += av.w * bv.w;
    }
  }

  int col = n0 + (tx << 2);
  if (kind == 0) {
    float4 bias = *(const float4*)(b1c + col);
#pragma unroll
    for (int i = 0; i < 4; i++) {
      int b = (ty << 2) + i;
      *(float4*)(g1p + (b << 12) + col) =
          make_float4(acc[i][0] + bias.x, acc[i][1] + bias.y, acc[i][2] + bias.z, acc[i][3] + bias.w);
    }
  } else if (kind == 1) {
    float4 bias = *(const float4*)(b2c + col);
#pragma unroll
    for (int i = 0; i < 4; i++) {
      int b = (ty << 2) + i;
      *(float4*)(g2p + (b << 12) + col) =
          make_float4(acc[i][0] + bias.x, acc[i][1] + bias.y, acc[i][2] + bias.z, acc[i][3] + bias.w);
    }
  } else {
    float4 bias = *(const float4*)(bqF + col);
#pragma unroll
    for (int i = 0; i < 4; i++) {
      int b = (ty << 2) + i;
      *(float4*)(qv + (b << 10) + col) =
          make_float4(acc[i][0] + bias.x, acc[i][1] + bias.y, acc[i][2] + bias.z, acc[i][3] + bias.w);
    }
  }
}

// ---------------------------------------------------------------------------
// FAST lstm GEMM: P[ks][64,4096] = x[64, ks*256..+256] @ W[4096, slice]^T
// grid 256 = 4 K-splits x 64 col tiles. W: Weff (fp32, fidx=-1) or wih2 (f9).
// ---------------------------------------------------------------------------
__global__ __launch_bounds__(256) void lstm_gemm(
    const float* __restrict__ x, const void* __restrict__ Wm,
    const int* __restrict__ flags, int fidx, float* __restrict__ P) {
  __shared__ __align__(16) float sX[32][68];
  __shared__ __align__(16) float sW[32][68];
  int bi = blockIdx.x, t = threadIdx.x;
  int ks = bi >> 6;
  int n0 = (bi & 63) << 6;
  int kbase = ks << 8;
  int bf = (fidx >= 0) ? flags[fidx] : 0;
  int lm = t >> 2, lk8 = (t & 3) << 3;
  int tx = t & 15, ty = t >> 4;
  float acc[4][4] = {};
  for (int kc = 0; kc < 256; kc += 32) {
    int koff = kbase + kc;
    float4 xa = *(const float4*)(x + (lm << 10) + koff + lk8);
    float4 xb = *(const float4*)(x + (lm << 10) + koff + lk8 + 4);
    float4 wa = ld4f(Wm, (size_t)(n0 + lm) * 1024 + koff + lk8, bf);
    float4 wb = ld4f(Wm, (size_t)(n0 + lm) * 1024 + koff + lk8 + 4, bf);
    __syncthreads();
    sX[lk8 + 0][lm] = xa.x; sX[lk8 + 1][lm] = xa.y; sX[lk8 + 2][lm] = xa.z; sX[lk8 + 3][lm] = xa.w;
    sX[lk8 + 4][lm] = xb.x; sX[lk8 + 5][lm] = xb.y; sX[lk8 + 6][lm] = xb.z; sX[lk8 + 7][lm] = xb.w;
    sW[lk8 + 0][lm] = wa.x; sW[lk8 + 1][lm] = wa.y; sW[lk8 + 2][lm] = wa.z; sW[lk8 + 3][lm] = wa.w;
    sW[lk8 + 4][lm] = wb.x; sW[lk8 + 5][lm] = wb.y; sW[lk8 + 6][lm] = wb.z; sW[lk8 + 7][lm] = wb.w;
    __syncthreads();
#pragma unroll
    for (int k = 0; k < 32; k++) {
      float4 av = *(const float4*)&sX[k][ty << 2];
      float4 bv = *(const float4*)&sW[k][tx << 2];
      acc[0][0] += av.x * bv.x; acc[0][1] += av.x * bv.y; acc[0][2] += av.x * bv.z; acc[0][3] += av.x * bv.w;
      acc[1][0] += av.y * bv.x; acc[1][1] += av.y * bv.y; acc[1][2] += av.y * bv.z; acc[1][3] += av.y * bv.w;
      acc[2][0] += av.z * bv.x; acc[2][1] += av.z * bv.y; acc[2][2] += av.z * bv.z; acc[2][3] += av.z * bv.w;
      acc[3][0] += av.w * bv.x; acc[3][1] += av.w * bv.y; acc[3][2] += av.w * bv.z; acc[3][3] += av.w * bv.w;
    }
  }
  int col = n0 + (tx << 2);
  float* Pk = P + ((size_t)ks << 18);
#pragma unroll
  for (int i = 0; i < 4; i++) {
    int b = (ty << 2) + i;
    *(float4*)(Pk + (b << 12) + col) = make_float4(acc[i][0], acc[i][1], acc[i][2], acc[i][3]);
  }
}

// FAST lstm elementwise: g = gpart + sum_ks P[ks]; c,h update. grid 256.
__global__ __launch_bounds__(256) void lstm_ew(
    const float* __restrict__ gp, const float* __restrict__ P,
    float* __restrict__ cbuf, float* __restrict__ hbuf) {
  int b = blockIdx.x >> 2;
  int j = ((blockIdx.x & 3) << 8) + threadIdx.x;
  int base = (b << 12) + j;
  float g[4];
#pragma unroll
  for (int gi = 0; gi < 4; gi++) {
    int idx = base + (gi << 10);
    g[gi] = gp[idx] + P[idx] + P[idx + (1 << 18)] + P[idx + (2 << 18)] + P[idx + (3 << 18)];
  }
  float gi_ = sigm(g[0]);
  float gf_ = sigm(g[1]);
  float gg_ = tanhf(g[2]);
  float go_ = sigm(g[3]);
  float c = gf_ * cbuf[(b << 10) + j] + gi_ * gg_;
  cbuf[(b << 10) + j] = c;
  hbuf[(b << 10) + j] = go_ * tanhf(c);
}

// ---------------------------------------------------------------------------
// Attention (shared): one block per (b,h); t = score index s, then ctx d.
// ---------------------------------------------------------------------------
__global__ __launch_bounds__(256) void attn_kernel(
    const float* __restrict__ qbuf, const float* __restrict__ Kt,
    const float* __restrict__ Vb, float* __restrict__ cr) {
  __shared__ float lq[256];
  __shared__ float latt[256];
  __shared__ float red[8];
  int p = blockIdx.x, t = threadIdx.x;
  int b = p >> 2, h = p & 3;
  lq[t] = qbuf[(b << 10) + (h << 8) + t];
  __syncthreads();
  const float* Kp = Kt + ((size_t)p << 16);
  float sc = 0.f;
#pragma unroll 4
  for (int d = 0; d < 256; d++) sc += lq[d] * Kp[(d << 8) + t];
  sc *= 0.0625f;
  float m = sc;
#pragma unroll
  for (int o = 32; o >= 1; o >>= 1) m = fmaxf(m, __shfl_xor(m, o, 64));
  if ((t & 63) == 0) red[t >> 6] = m;
  __syncthreads();
  m = fmaxf(fmaxf(red[0], red[1]), fmaxf(red[2], red[3]));
  float e = __expf(sc - m);
  float ss = e;
#pragma unroll
  for (int o = 32; o >= 1; o >>= 1) ss += __shfl_xor(ss, o, 64);
  if ((t & 63) == 0) red[4 + (t >> 6)] = ss;
  __syncthreads();
  ss = red[4] + red[5] + red[6] + red[7];
  latt[t] = e / ss;
  __syncthreads();
  const float* Vp = Vb + ((size_t)p << 16);
  float cv = 0.f;
#pragma unroll 4
  for (int s2 = 0; s2 < 256; s2++) cv += latt[s2] * Vp[(s2 << 8) + t];
  cr[(b << 10) + (h << 8) + t] = cv;
}

// final output head (shared)
__global__ __launch_bounds__(256) void outhead_kernel(
    const float* __restrict__ h2, const void* __restrict__ wout,
    const int* __restrict__ flags, const float* __restrict__ boutF,
    float* __restrict__ out, int row) {
  __shared__ float smem[1280];
  int b = blockIdx.x, t = threadIdx.x;
  int f13 = flags[13];
  float p[5] = {0.f, 0.f, 0.f, 0.f, 0.f};
#pragma unroll
  for (int k2 = 0; k2 < 4; k2++) {
    float hv = h2[(b << 10) + t + (k2 << 8)];
#pragma unroll
    for (int v = 0; v < 5; v++)
      p[v] += hv * ld1f(wout, (size_t)(v << 10) + t + (k2 << 8), f13);
  }
#pragma unroll
  for (int v = 0; v < 5; v++) smem[v * 256 + t] = p[v];
  __syncthreads();
  if (t < 5) {
    float acc = boutF[t];
    for (int i = 0; i < 256; i++) acc += smem[t * 256 + i];
    if (t >= 2) acc = sigm(acc);
    out[(row * 64 + b) * 5 + t] = acc;
  }
}

// ========================= SLOW PATH (round-4, proven) =====================
__global__ __launch_bounds__(256) void p1_kernel(
    const float* __restrict__ h1, const float* __restrict__ h2,
    const void* __restrict__ wih1, const void* __restrict__ whh1,
    const void* __restrict__ whh2, const void* __restrict__ wqkv,
    const void* __restrict__ wout, const int* __restrict__ flags,
    const float* __restrict__ b1c, const float* __restrict__ b2c,
    const float* __restrict__ bqF, const float* __restrict__ boutF,
    float* __restrict__ g1p, float* __restrict__ g2p,
    float* __restrict__ qbuf, float* __restrict__ out, int s) {
  __shared__ float smem[2048];
  int bi = blockIdx.x, t = threadIdx.x;
  if (bi < 1024) {
    int f5 = flags[5], f6 = flags[6], f10 = flags[10];
    int b = bi & 63, jt = bi >> 6;
    float4* s2 = (float4*)smem;
    float4* s1 = (float4*)(smem + 1024);
    s2[t] = ((const float4*)(h2 + (b << 10)))[t];
    s1[t] = ((const float4*)(h1 + (b << 10)))[t];
    __syncthreads();
    int j = (jt << 8) + t;
    size_t ra = (size_t)j * 2048, rb = (size_t)j * 1024;
    float a1 = 0.f, a3 = 0.f;
#pragma unroll 2
    for (int i = 0; i < 256; i++) {
      float4 A4 = ld4f(wih1, ra + 4 * i, f5);
      float4 B4 = ld4f(whh1, rb + 4 * i, f6);
      float4 C4 = ld4f(whh2, rb + 4 * i, f10);
      float4 x2 = s2[i], x1 = s1[i];
      a1 += x2.x * A4.x + x2.y * A4.y + x2.z * A4.z + x2.w * A4.w;
      a1 += x1.x * B4.x + x1.y * B4.y + x1.z * B4.z + x1.w * B4.w;
      a3 += x2.x * C4.x + x2.y * C4.y + x2.z * C4.z + x2.w * C4.w;
    }
    g1p[(b << 12) + j] = a1 + b1c[j];
    g2p[(b << 12) + j] = a3 + b2c[j];
  } else if (bi < 1280) {
    int f1 = flags[1];
    int idx = bi - 1024;
    int b = idx & 63, dt = idx >> 6;
    float4* s2 = (float4*)smem;
    s2[t] = ((const float4*)(h2 + (b << 10)))[t];
    __syncthreads();
    int col = (dt << 8) + t;
    size_t r = (size_t)col * 1024;
    float acc = 0.f;
#pragma unroll 4
    for (int i = 0; i < 256; i++) {
      float4 w4 = ld4f(wqkv, r + 4 * i, f1);
      float4 x = s2[i];
      acc += x.x * w4.x + x.y * w4.y + x.z * w4.z + x.w * w4.w;
    }
    qbuf[(b << 10) + col] = acc + bqF[col];
  } else {
    if (s == 0) return;
    int f13 = flags[13];
    int b = bi - 1280;
    float p[5] = {0.f, 0.f, 0.f, 0.f, 0.f};
#pragma unroll
    for (int k2 = 0; k2 < 4; k2++) {
      float hv = h2[(b << 10) + t + (k2 << 8)];
#pragma unroll
      for (int v = 0; v < 5; v++)
        p[v] += hv * ld1f(wout, (size_t)(v << 10) + t + (k2 << 8), f13);
    }
#pragma unroll
    for (int v = 0; v < 5; v++) smem[v * 256 + t] = p[v];
    __syncthreads();
    if (t < 5) {
      float acc = boutF[t];
      for (int i = 0; i < 256; i++) acc += smem[t * 256 + i];
      if (t >= 2) acc = sigm(acc);
      out[((s - 1) * 64 + b) * 5 + t] = acc;
    }
  }
}

__global__ __launch_bounds__(256) void oproj_kernel(
    const float* __restrict__ cr, const void* __restrict__ wo,
    const int* __restrict__ flags, const float* __restrict__ boF,
    float* __restrict__ cx) {
  __shared__ float lx[1024];
  int idx = blockIdx.x, b = idx & 63, dt = idx >> 6, t = threadIdx.x;
  ((float4*)lx)[t] = ((const float4*)(cr + (b << 10)))[t];
  __syncthreads();
  int f3 = flags[3];
  int col = (dt << 8) + t;
  size_t r = (size_t)col * 1024;
  float acc = 0.f;
#pragma unroll 4
  for (int i = 0; i < 256; i++) {
    float4 w4 = ld4f(wo, r + 4 * i, f3);
    float4 x = ((float4*)lx)[i];
    acc += x.x * w4.x + x.y * w4.y + x.z * w4.z + x.w * w4.w;
  }
  cx[(b << 10) + col] = acc + boF[col];
}

__global__ __launch_bounds__(256) void lstm_kernel(
    const float* __restrict__ xin, const void* __restrict__ Wg,
    const int* __restrict__ flags, int fidx, int rowStride, int colOff,
    const float* __restrict__ gpart, float* __restrict__ cbuf,
    float* __restrict__ hbuf) {
  __shared__ float lx[1024];
  int b = blockIdx.x >> 2, j0 = (blockIdx.x & 3) << 8;
  int t = threadIdx.x;
  ((float4*)lx)[t] = ((const float4*)(xin + (b << 10)))[t];
  __syncthreads();
  int bf = flags[fidx];
  int j = j0 + t;
  float g[4];
#pragma unroll
  for (int gi = 0; gi < 4; gi++) {
    size_t r = (size_t)((gi << 10) + j) * rowStride + colOff;
    float acc = 0.f;
#pragma unroll 4
    for (int i = 0; i < 256; i++) {
      float4 w4 = ld4f(Wg, r + 4 * i, bf);
      float4 x = ((float4*)lx)[i];
      acc += x.x * w4.x + x.y * w4.y + x.z * w4.z + x.w * w4.w;
    }
    g[gi] = gpart[(b << 12) + (gi << 10) + j] + acc;
  }
  float gi_ = sigm(g[0]);
  float gf_ = sigm(g[1]);
  float gg_ = tanhf(g[2]);
  float go_ = sigm(g[3]);
  float c = gf_ * cbuf[(b << 10) + j] + gi_ * gg_;
  cbuf[(b << 10) + j] = c;
  hbuf[(b << 10) + j] = go_ * tanhf(c);
}

// ===========================================================================
extern "C" void kernel_launch(void* const* d_in, const int* in_sizes, int n_in,
                              void* d_out, int out_size, void* d_ws, size_t ws_size,
                              hipStream_t stream) {
  float* out = (float*)d_out;
  float* W = (float*)d_ws;

  Ptrs pp;
  for (int i = 0; i < 15; i++) { pp.p[i] = d_in[i]; pp.n[i] = in_sizes[i]; }

  if (ws_size >= FWS_NEED) {
    // ---------------- FAST PATH ----------------
    float* h1    = W + OFF_H1;
    float* c1    = W + OFF_C1;
    float* h2    = W + OFF_H2;
    float* c2    = W + OFF_C2;
    float* qv    = W + FOFF_QV;
    float* cr    = W + FOFF_CR;
    float* g1p   = W + FOFF_G1P;
    float* g2p   = W + FOFF_G2P;
    float* P     = W + FOFF_P;
    float* b1c   = W + FOFF_B1C;
    float* b2c   = W + FOFF_B2C;
    float* bqF   = W + FOFF_BQ;
    float* boF   = W + FOFF_BO;
    float* boutF = W + FOFF_BOUT;
    int*   flags = (int*)(W + FOFF_FLAGS);
    float* Weff  = W + FOFF_WEFF;
    float* Kt    = W + FOFF_KT;
    float* Vb    = W + FOFF_VB;

    hipMemsetAsync(d_ws, 0, 4 * 65536 * sizeof(float), stream);
    detect_kernel<<<1, 64, 0, stream>>>(pp, flags);
    bias_cvt<<<16, 256, 0, stream>>>(d_in[2], d_in[4], d_in[7], d_in[8],
                                     d_in[11], d_in[12], d_in[14], flags,
                                     bqF, boF, b1c, b2c, boutF);
    bias_fold<<<16, 256, 0, stream>>>(d_in[5], flags, boF, b1c);
    weff_gemm<<<dim3(16, 64), 256, 0, stream>>>(d_in[5], d_in[3], flags, Weff);
    kv_gemm<<<dim3(32, 256), 256, 0, stream>>>(d_in[0], d_in[1], flags, bqF, Kt, Vb);

    for (int s = 0; s < S_LEN; s++) {
      p1_fast<<<208, 256, 0, stream>>>(h1, h2, d_in[5], d_in[6], d_in[10],
                                       d_in[1], d_in[13], flags, b1c, b2c,
                                       bqF, boutF, g1p, g2p, qv, out, s);
      attn_kernel<<<256, 256, 0, stream>>>(qv, Kt, Vb, cr);
      lstm_gemm<<<256, 256, 0, stream>>>(cr, Weff, flags, -1, P);
      lstm_ew<<<256, 256, 0, stream>>>(g1p, P, c1, h1);
      lstm_gemm<<<256, 256, 0, stream>>>(h1, d_in[9], flags, 9, P);
      lstm_ew<<<256, 256, 0, stream>>>(g2p, P, c2, h2);
    }
    outhead_kernel<<<64, 256, 0, stream>>>(h2, d_in[13], flags, boutF, out, 255);
  } else if (ws_size >= WS_NEED) {
    // ---------------- SLOW PATH (round-4, proven) ----------------
    float* h1    = W + OFF_H1;
    float* c1    = W + OFF_C1;
    float* h2    = W + OFF_H2;
    float* c2    = W + OFF_C2;
    float* qvb   = W + OFF_Q;
    float* cr    = W + OFF_CR;
    float* cx    = W + OFF_CX;
    float* g1p   = W + OFF_G1;
    float* g2p   = W + OFF_G2;
    float* b1c   = W + OFF_B1C;
    float* b2c   = W + OFF_B2C;
    float* bqF   = W + OFF_BQ;
    float* boF   = W + OFF_BO;
    float* boutF = W + OFF_BOUT;
    int*   flags = (int*)(W + OFF_FLAGS);
    float* Kt    = W + OFF_KT;
    float* Vb    = W + OFF_VB;

    hipMemsetAsync(d_ws, 0, 4 * 65536 * sizeof(float), stream);
    detect_kernel<<<1, 64, 0, stream>>>(pp, flags);
    bias_cvt<<<16, 256, 0, stream>>>(d_in[2], d_in[4], d_in[7], d_in[8],
                                     d_in[11], d_in[12], d_in[14], flags,
                                     bqF, boF, b1c, b2c, boutF);
    kv_gemm<<<dim3(32, 256), 256, 0, stream>>>(d_in[0], d_in[1], flags, bqF, Kt, Vb);

    for (int s = 0; s < S_LEN; s++) {
      p1_kernel<<<1344, 256, 0, stream>>>(h1, h2, d_in[5], d_in[6], d_in[10],
                                          d_in[1], d_in[13], flags, b1c, b2c,
                                          bqF, boutF, g1p, g2p, qvb, out, s);
      attn_kernel<<<256, 256, 0, stream>>>(qvb, Kt, Vb, cr);
      oproj_kernel<<<256, 256, 0, stream>>>(cr, d_in[3], flags, boF, cx);
      lstm_kernel<<<256, 256, 0, stream>>>(cx, d_in[5], flags, 5, 2048, 1024, g1p, c1, h1);
      lstm_kernel<<<256, 256, 0, stream>>>(h1, d_in[9], flags, 9, 1024, 0, g2p, c2, h2);
    }
    outhead_kernel<<<64, 256, 0, stream>>>(h2, d_in[13], flags, boutF, out, 255);
  }
}